// Round 1
// baseline (177.088 us; speedup 1.0000x reference)
//
#include <hip/hip_runtime.h>

#define WAVES_PER_BLOCK 4

// One wave (64 lanes) per edge.
// Row is 128 f32 = 512B = 64 lanes x float2  -> perfectly coalesced gather.
// |row - col| . W  computed as per-lane partial + 64-lane shfl_xor butterfly.
__global__ __launch_bounds__(256) void edge_score_kernel(
    const float* __restrict__ inputs,   // [N,128] f32
    const int*   __restrict__ r_idx,    // [E] i32
    const int*   __restrict__ c_idx,    // [E] i32
    const float* __restrict__ W,        // [128,1] f32
    const float* __restrict__ bias_p,   // [1] f32
    float*       __restrict__ out,      // [E] f32
    int E)
{
    const int lane   = threadIdx.x & 63;
    const int wid    = threadIdx.x >> 6;
    const int gwave  = blockIdx.x * WAVES_PER_BLOCK + wid;
    const int nwaves = gridDim.x * WAVES_PER_BLOCK;

    // Per-lane weight pair (D=128 -> 2 floats/lane) and bias: loaded once.
    const float2 w    = ((const float2*)W)[lane];
    const float  bias = bias_p[0];

    for (int e = gwave; e < E; e += nwaves) {
        const int r = r_idx[e];
        const int c = c_idx[e];
        const float2 a = ((const float2*)(inputs + (size_t)r * 128))[lane];
        const float2 b = ((const float2*)(inputs + (size_t)c * 128))[lane];

        float partial = fabsf(a.x - b.x) * w.x + fabsf(a.y - b.y) * w.y;

        // 64-lane butterfly reduction (wave = 64 on CDNA!)
        #pragma unroll
        for (int off = 32; off > 0; off >>= 1)
            partial += __shfl_xor(partial, off, 64);

        if (lane == 0) out[e] = partial + bias;
    }
}

extern "C" void kernel_launch(void* const* d_in, const int* in_sizes, int n_in,
                              void* d_out, int out_size, void* d_ws, size_t ws_size,
                              hipStream_t stream) {
    const float* inputs = (const float*)d_in[0];
    const int*   r_idx  = (const int*)d_in[1];
    const int*   c_idx  = (const int*)d_in[2];
    const float* W      = (const float*)d_in[3];
    const float* b      = (const float*)d_in[4];
    float*       out    = (float*)d_out;

    const int E = in_sizes[1];   // 600000 edges

    // 2048 blocks x 4 waves = 8192 waves = 32 waves/CU -> full occupancy,
    // grid-stride over edges.
    const int blocks = 2048;
    edge_score_kernel<<<blocks, 256, 0, stream>>>(inputs, r_idx, c_idx, W, b, out, E);
}

// Round 2
// 163.425 us; speedup vs baseline: 1.0836x; 1.0836x over previous
//
#include <hip/hip_runtime.h>

#define WAVES_PER_BLOCK 4
#define U 8   // edges per wave per iteration (MLP depth = 16 row-gathers in flight)

// One wave (64 lanes) per edge, 8 edges in flight per iteration.
// Row is 128 f32 = 512B = 64 lanes x float2 -> perfectly coalesced gather.
// |row - col| . W  computed as per-lane partial + 64-lane shfl_xor butterfly.
__global__ __launch_bounds__(256) void edge_score_kernel(
    const float* __restrict__ inputs,   // [N,128] f32
    const int*   __restrict__ r_idx,    // [E] i32
    const int*   __restrict__ c_idx,    // [E] i32
    const float* __restrict__ W,        // [128,1] f32
    const float* __restrict__ bias_p,   // [1] f32
    float*       __restrict__ out,      // [E] f32
    int E)
{
    const int lane   = threadIdx.x & 63;
    const int wid    = threadIdx.x >> 6;
    const int gwave  = blockIdx.x * WAVES_PER_BLOCK + wid;
    const int nwaves = gridDim.x * WAVES_PER_BLOCK;

    // Per-lane weight pair (D=128 -> 2 floats/lane) and bias: loaded once.
    const float2 w    = ((const float2*)W)[lane];
    const float  bias = bias_p[0];

    const int Efull = E & ~(U - 1);

    for (int e0 = gwave * U; e0 < Efull; e0 += nwaves * U) {
        // Issue all index loads first (sequential, cache-hot) ...
        int r[U], c[U];
        #pragma unroll
        for (int i = 0; i < U; ++i) {
            r[i] = r_idx[e0 + i];
            c[i] = c_idx[e0 + i];
        }
        // ... then all 16 row-gathers so they are simultaneously in flight.
        float2 a[U], b[U];
        #pragma unroll
        for (int i = 0; i < U; ++i) {
            a[i] = ((const float2*)(inputs + (size_t)r[i] * 128))[lane];
            b[i] = ((const float2*)(inputs + (size_t)c[i] * 128))[lane];
        }

        float p[U];
        #pragma unroll
        for (int i = 0; i < U; ++i)
            p[i] = fabsf(a[i].x - b[i].x) * w.x + fabsf(a[i].y - b[i].y) * w.y;

        // 8 independent 64-lane butterflies (interleaved by the scheduler).
        #pragma unroll
        for (int off = 32; off > 0; off >>= 1) {
            #pragma unroll
            for (int i = 0; i < U; ++i)
                p[i] += __shfl_xor(p[i], off, 64);
        }

        // Every lane now holds each full sum; lanes 0..7 write 8 consecutive
        // outputs (coalesced 32B). Select chain keeps indexing compile-time.
        float v = p[0];
        #pragma unroll
        for (int i = 1; i < U; ++i)
            v = (lane == i) ? p[i] : v;
        if (lane < U) out[e0 + lane] = v + bias;
    }

    // Tail: one edge per wave, simple path.
    for (int e = Efull + gwave; e < E; e += nwaves) {
        const int rr = r_idx[e];
        const int cc = c_idx[e];
        const float2 a = ((const float2*)(inputs + (size_t)rr * 128))[lane];
        const float2 b = ((const float2*)(inputs + (size_t)cc * 128))[lane];
        float partial = fabsf(a.x - b.x) * w.x + fabsf(a.y - b.y) * w.y;
        #pragma unroll
        for (int off = 32; off > 0; off >>= 1)
            partial += __shfl_xor(partial, off, 64);
        if (lane == 0) out[e] = partial + bias;
    }
}

extern "C" void kernel_launch(void* const* d_in, const int* in_sizes, int n_in,
                              void* d_out, int out_size, void* d_ws, size_t ws_size,
                              hipStream_t stream) {
    const float* inputs = (const float*)d_in[0];
    const int*   r_idx  = (const int*)d_in[1];
    const int*   c_idx  = (const int*)d_in[2];
    const float* W      = (const float*)d_in[3];
    const float* b      = (const float*)d_in[4];
    float*       out    = (float*)d_out;

    const int E = in_sizes[1];   // 600000 edges

    // 2048 blocks x 4 waves = 8192 waves = 32 waves/CU -> full occupancy,
    // grid-stride over edge groups.
    const int blocks = 2048;
    edge_score_kernel<<<blocks, 256, 0, stream>>>(inputs, r_idx, c_idx, W, b, out, E);
}

// Round 7
// 140.154 us; speedup vs baseline: 1.2635x; 1.1660x over previous
//
#include <hip/hip_runtime.h>

#define WAVES_PER_BLOCK 4
#define U 8   // edges per wave per iteration

// ---- helpers -------------------------------------------------------------

__device__ inline unsigned short f2bf_rne(float f) {
    unsigned u = __float_as_uint(f);
    u += 0x7FFFu + ((u >> 16) & 1u);
    return (unsigned short)(u >> 16);
}

// one u32 = 2 packed bf16 -> float2 (2 VALU ops)
__device__ inline float2 bf2_to_f2(unsigned u) {
    float2 f;
    f.x = __uint_as_float(u << 16);
    f.y = __uint_as_float(u & 0xFFFF0000u);
    return f;
}

// ---- pass 1: f32 table -> bf16 table in d_ws -----------------------------

__global__ __launch_bounds__(256) void convert_kernel(
    const float* __restrict__ in,        // [N*D] f32
    unsigned short* __restrict__ out,    // [N*D] bf16
    int n4)                              // N*D/4
{
    int i = blockIdx.x * blockDim.x + threadIdx.x;
    const int stride = gridDim.x * blockDim.x;
    for (; i < n4; i += stride) {
        float4 v = ((const float4*)in)[i];
        ushort4 o;
        o.x = f2bf_rne(v.x);
        o.y = f2bf_rne(v.y);
        o.z = f2bf_rne(v.z);
        o.w = f2bf_rne(v.w);
        ((ushort4*)out)[i] = o;
    }
}

// ---- pass 2: gather bf16 rows, |a-b|.W + bias ----------------------------
// One wave per edge, U edges in flight. Row = 128 bf16 = 256B = 64 lanes x 1
// dword (2 bf16)  -> coalesced, 4 cache lines per row (half of f32 path).

__global__ __launch_bounds__(256) void edge_score_bf16_kernel(
    const unsigned* __restrict__ table,  // [N*64] u32 (packed bf16 pairs)
    const int*   __restrict__ r_idx,
    const int*   __restrict__ c_idx,
    const float* __restrict__ W,         // [128] f32
    const float* __restrict__ bias_p,
    float*       __restrict__ out,
    int E)
{
    const int lane   = threadIdx.x & 63;
    const int wid    = threadIdx.x >> 6;
    const int gwave  = blockIdx.x * WAVES_PER_BLOCK + wid;
    const int nwaves = gridDim.x * WAVES_PER_BLOCK;

    const float2 w    = ((const float2*)W)[lane];
    const float  bias = bias_p[0];

    const int Efull = E & ~(U - 1);

    for (int e0 = gwave * U; e0 < Efull; e0 += nwaves * U) {
        int r[U], c[U];
        #pragma unroll
        for (int i = 0; i < U; ++i) {
            r[i] = r_idx[e0 + i];
            c[i] = c_idx[e0 + i];
        }
        unsigned ua[U], ub[U];
        #pragma unroll
        for (int i = 0; i < U; ++i) {
            ua[i] = table[(size_t)r[i] * 64 + lane];
            ub[i] = table[(size_t)c[i] * 64 + lane];
        }

        float p[U];
        #pragma unroll
        for (int i = 0; i < U; ++i) {
            float2 a = bf2_to_f2(ua[i]);
            float2 b = bf2_to_f2(ub[i]);
            p[i] = fabsf(a.x - b.x) * w.x + fabsf(a.y - b.y) * w.y;
        }

        #pragma unroll
        for (int off = 32; off > 0; off >>= 1) {
            #pragma unroll
            for (int i = 0; i < U; ++i)
                p[i] += __shfl_xor(p[i], off, 64);
        }

        float v = p[0];
        #pragma unroll
        for (int i = 1; i < U; ++i)
            v = (lane == i) ? p[i] : v;
        if (lane < U) out[e0 + lane] = v + bias;
    }

    for (int e = Efull + gwave; e < E; e += nwaves) {
        const int rr = r_idx[e];
        const int cc = c_idx[e];
        float2 a = bf2_to_f2(table[(size_t)rr * 64 + lane]);
        float2 b = bf2_to_f2(table[(size_t)cc * 64 + lane]);
        float partial = fabsf(a.x - b.x) * w.x + fabsf(a.y - b.y) * w.y;
        #pragma unroll
        for (int off = 32; off > 0; off >>= 1)
            partial += __shfl_xor(partial, off, 64);
        if (lane == 0) out[e] = partial + bias;
    }
}

// ---- fallback: original f32 path (used only if ws too small) -------------

__global__ __launch_bounds__(256) void edge_score_f32_kernel(
    const float* __restrict__ inputs,
    const int*   __restrict__ r_idx,
    const int*   __restrict__ c_idx,
    const float* __restrict__ W,
    const float* __restrict__ bias_p,
    float*       __restrict__ out,
    int E)
{
    const int lane   = threadIdx.x & 63;
    const int wid    = threadIdx.x >> 6;
    const int gwave  = blockIdx.x * WAVES_PER_BLOCK + wid;
    const int nwaves = gridDim.x * WAVES_PER_BLOCK;

    const float2 w    = ((const float2*)W)[lane];
    const float  bias = bias_p[0];

    for (int e = gwave; e < E; e += nwaves) {
        const int r = r_idx[e];
        const int c = c_idx[e];
        const float2 a = ((const float2*)(inputs + (size_t)r * 128))[lane];
        const float2 b = ((const float2*)(inputs + (size_t)c * 128))[lane];
        float partial = fabsf(a.x - b.x) * w.x + fabsf(a.y - b.y) * w.y;
        #pragma unroll
        for (int off = 32; off > 0; off >>= 1)
            partial += __shfl_xor(partial, off, 64);
        if (lane == 0) out[e] = partial + bias;
    }
}

extern "C" void kernel_launch(void* const* d_in, const int* in_sizes, int n_in,
                              void* d_out, int out_size, void* d_ws, size_t ws_size,
                              hipStream_t stream) {
    const float* inputs = (const float*)d_in[0];
    const int*   r_idx  = (const int*)d_in[1];
    const int*   c_idx  = (const int*)d_in[2];
    const float* W      = (const float*)d_in[3];
    const float* b      = (const float*)d_in[4];
    float*       out    = (float*)d_out;

    const int N_D = in_sizes[0];        // 100000 * 128
    const int E   = in_sizes[1];        // 600000

    const size_t bf16_bytes = (size_t)N_D * 2;

    if (ws_size >= bf16_bytes) {
        unsigned short* table_bf16 = (unsigned short*)d_ws;
        convert_kernel<<<2048, 256, 0, stream>>>(inputs, table_bf16, N_D / 4);
        edge_score_bf16_kernel<<<2048, 256, 0, stream>>>(
            (const unsigned*)table_bf16, r_idx, c_idx, W, b, out, E);
    } else {
        edge_score_f32_kernel<<<2048, 256, 0, stream>>>(
            inputs, r_idx, c_idx, W, b, out, E);
    }
}

// Round 9
// 135.179 us; speedup vs baseline: 1.3100x; 1.0368x over previous
//
#include <hip/hip_runtime.h>

#define WAVES_PER_BLOCK 4
#define U 8   // edges per wave per iteration (4 pairs; 8 row-gather instrs in flight)

// ---- helpers -------------------------------------------------------------

__device__ inline unsigned short f2bf_rne(float f) {
    unsigned u = __float_as_uint(f);
    u += 0x7FFFu + ((u >> 16) & 1u);
    return (unsigned short)(u >> 16);
}

// one u32 = 2 packed bf16 -> float2
__device__ inline float2 bf2_to_f2(unsigned u) {
    float2 f;
    f.x = __uint_as_float(u << 16);
    f.y = __uint_as_float(u & 0xFFFF0000u);
    return f;
}

// ---- pass 1: f32 table -> bf16 table in d_ws -----------------------------

__global__ __launch_bounds__(256) void convert_kernel(
    const float* __restrict__ in,        // [N*D] f32
    unsigned short* __restrict__ out,    // [N*D] bf16
    int n4)                              // N*D/4
{
    int i = blockIdx.x * blockDim.x + threadIdx.x;
    const int stride = gridDim.x * blockDim.x;
    for (; i < n4; i += stride) {
        float4 v = ((const float4*)in)[i];
        ushort4 o;
        o.x = f2bf_rne(v.x);
        o.y = f2bf_rne(v.y);
        o.z = f2bf_rne(v.z);
        o.w = f2bf_rne(v.w);
        ((ushort4*)out)[i] = o;
    }
}

// ---- pass 2: half-wave-per-row gather ------------------------------------
// Lanes 0-31 own the EVEN edge of a pair, lanes 32-63 the ODD edge.
// Each lane loads uint2 (4 bf16) at dword-pair `sub` of its edge's row:
// one vmem instruction covers two full 256B rows (8 lines, same as before,
// but 1 instr/edge instead of 2). Reduction: 5-step butterfly within each
// 32-lane half (xor 16..1 never crosses bit 5) -> 2.5 shfl/edge vs 6.

__global__ __launch_bounds__(256) void edge_score_bf16_pair_kernel(
    const unsigned* __restrict__ table,  // [N*64] u32 (packed bf16 pairs)
    const int*   __restrict__ r_idx,
    const int*   __restrict__ c_idx,
    const float* __restrict__ W,         // [128] f32
    const float* __restrict__ bias_p,
    float*       __restrict__ out,
    int E)
{
    const int lane = threadIdx.x & 63;
    const int half = lane >> 5;          // 0 = even edge of pair, 1 = odd
    const int sub  = lane & 31;          // which dword-pair (8B) of the row
    const int wid  = threadIdx.x >> 6;
    const int gwave  = blockIdx.x * WAVES_PER_BLOCK + wid;
    const int nwaves = gridDim.x * WAVES_PER_BLOCK;

    // lane `sub` owns elements 4*sub .. 4*sub+3 of the row
    const float4 w4   = ((const float4*)W)[sub];
    const float  bias = bias_p[0];

    const int Efull = E & ~(U - 1);

    for (int e0 = gwave * U; e0 < Efull; e0 += nwaves * U) {
        // index loads: per pair, low half loads even edge, high half odd
        int re[U / 2], ce[U / 2];
        #pragma unroll
        for (int i = 0; i < U / 2; ++i) {
            const int e = e0 + 2 * i + half;
            re[i] = r_idx[e];
            ce[i] = c_idx[e];
        }
        // all row-gathers issued back-to-back (memory-level parallelism)
        uint2 ra[U / 2], ca[U / 2];
        #pragma unroll
        for (int i = 0; i < U / 2; ++i) {
            ra[i] = ((const uint2*)table)[(size_t)re[i] * 32 + sub];
            ca[i] = ((const uint2*)table)[(size_t)ce[i] * 32 + sub];
        }

        float outv = 0.0f;
        #pragma unroll
        for (int i = 0; i < U / 2; ++i) {
            float2 rx = bf2_to_f2(ra[i].x);
            float2 ry = bf2_to_f2(ra[i].y);
            float2 cx = bf2_to_f2(ca[i].x);
            float2 cy = bf2_to_f2(ca[i].y);
            float p = fabsf(rx.x - cx.x) * w4.x + fabsf(rx.y - cx.y) * w4.y
                    + fabsf(ry.x - cy.x) * w4.z + fabsf(ry.y - cy.y) * w4.w;

            // butterfly within each 32-lane half (independent per half)
            #pragma unroll
            for (int off = 16; off > 0; off >>= 1)
                p += __shfl_xor(p, off, 64);

            // low half now holds even-edge sum, high half odd-edge sum.
            // collector: lane with (lane&31)>>1 == i keeps p.
            outv = (((lane & 31) >> 1) == i) ? p : outv;
        }

        // writer lanes: low half writes even slots, high half odd slots;
        // out index = e0 + (lane&31) for both groups.
        if ((sub < U) && (half == (lane & 1)))
            out[e0 + sub] = outv + bias;
    }

    // tail (empty for E % U == 0): one edge per wave, full-wave reduce
    for (int e = Efull + gwave; e < E; e += nwaves) {
        const int rr = r_idx[e];
        const int cc = c_idx[e];
        // full-wave path: each lane loads one dword of each row
        float2 a = bf2_to_f2(table[(size_t)rr * 64 + lane]);
        float2 b = bf2_to_f2(table[(size_t)cc * 64 + lane]);
        const float2 w2 = ((const float2*)W)[lane];
        float partial = fabsf(a.x - b.x) * w2.x + fabsf(a.y - b.y) * w2.y;
        #pragma unroll
        for (int off = 32; off > 0; off >>= 1)
            partial += __shfl_xor(partial, off, 64);
        if (lane == 0) out[e] = partial + bias;
    }
}

// ---- fallback: original f32 path (used only if ws too small) -------------

__global__ __launch_bounds__(256) void edge_score_f32_kernel(
    const float* __restrict__ inputs,
    const int*   __restrict__ r_idx,
    const int*   __restrict__ c_idx,
    const float* __restrict__ W,
    const float* __restrict__ bias_p,
    float*       __restrict__ out,
    int E)
{
    const int lane   = threadIdx.x & 63;
    const int wid    = threadIdx.x >> 6;
    const int gwave  = blockIdx.x * WAVES_PER_BLOCK + wid;
    const int nwaves = gridDim.x * WAVES_PER_BLOCK;

    const float2 w    = ((const float2*)W)[lane];
    const float  bias = bias_p[0];

    for (int e = gwave; e < E; e += nwaves) {
        const int r = r_idx[e];
        const int c = c_idx[e];
        const float2 a = ((const float2*)(inputs + (size_t)r * 128))[lane];
        const float2 b = ((const float2*)(inputs + (size_t)c * 128))[lane];
        float partial = fabsf(a.x - b.x) * w.x + fabsf(a.y - b.y) * w.y;
        #pragma unroll
        for (int off = 32; off > 0; off >>= 1)
            partial += __shfl_xor(partial, off, 64);
        if (lane == 0) out[e] = partial + bias;
    }
}

extern "C" void kernel_launch(void* const* d_in, const int* in_sizes, int n_in,
                              void* d_out, int out_size, void* d_ws, size_t ws_size,
                              hipStream_t stream) {
    const float* inputs = (const float*)d_in[0];
    const int*   r_idx  = (const int*)d_in[1];
    const int*   c_idx  = (const int*)d_in[2];
    const float* W      = (const float*)d_in[3];
    const float* b      = (const float*)d_in[4];
    float*       out    = (float*)d_out;

    const int N_D = in_sizes[0];        // 100000 * 128
    const int E   = in_sizes[1];        // 600000

    const size_t bf16_bytes = (size_t)N_D * 2;

    if (ws_size >= bf16_bytes) {
        unsigned short* table_bf16 = (unsigned short*)d_ws;
        convert_kernel<<<2048, 256, 0, stream>>>(inputs, table_bf16, N_D / 4);
        edge_score_bf16_pair_kernel<<<2048, 256, 0, stream>>>(
            (const unsigned*)table_bf16, r_idx, c_idx, W, b, out, E);
    } else {
        edge_score_f32_kernel<<<2048, 256, 0, stream>>>(
            inputs, r_idx, c_idx, W, b, out, E);
    }
}